// Round 6
// baseline (609.997 us; speedup 1.0000x reference)
//
#include <hip/hip_runtime.h>
#include <hip/hip_bf16.h>

#define N_NODES 10000
#define N_EDGES 320000
#define DIM     256
#define N_LAYERS 5
#define N_GRAPHS 128
#define RWSE_K  16

typedef __bf16 bf16_t;
typedef bf16_t bf16x8 __attribute__((ext_vector_type(8)));
typedef float  f32x4  __attribute__((ext_vector_type(4)));

__device__ inline ushort f2bf(float f) {
    union { float f; unsigned u; } v; v.f = f;
    unsigned r = v.u + 0x7fff + ((v.u >> 16) & 1);
    return (ushort)(r >> 16);
}
__device__ inline float bfbits2f(unsigned hi16) {
    union { unsigned u; float f; } v; v.u = hi16;
    return v.f;
}

// ---------------- fused setup: embed + edge-count + weight conv + BN fold ----
__global__ __launch_bounds__(256)
void setup_kernel(const int* __restrict__ feat_id,
                  const float* __restrict__ rwse,
                  const int* __restrict__ in_deg,
                  const float* __restrict__ w_val,
                  const float* __restrict__ b_val,
                  const float* __restrict__ w_rwse,
                  const float* __restrict__ b_rwse,
                  const float* __restrict__ deg_emb,
                  float* __restrict__ h, ushort* __restrict__ hb,
                  const int* __restrict__ ei, int* __restrict__ cnt_arr,
                  const float* __restrict__ w1, const float* __restrict__ w2,
                  ushort* __restrict__ wt1, ushort* __restrict__ wt2,
                  const float* __restrict__ gamma, const float* __restrict__ beta,
                  const float* __restrict__ mean, const float* __restrict__ var,
                  const float* __restrict__ b2, float* __restrict__ scale,
                  float* __restrict__ shift) {
    __shared__ float r[RWSE_K];
    __shared__ float t[32][33];
    int b = blockIdx.x;
    int tid = threadIdx.x;
    if (b < N_NODES) {
        int i = b, d = tid;
        if (d < RWSE_K) r[d] = rwse[i * RWSE_K + d];
        __syncthreads();
        int hid = feat_id[i] & (DIM - 1);
        int dg = in_deg[i];
        dg = dg < 0 ? 0 : (dg > 1000 ? 1000 : dg);
        float v = w_val[hid * DIM + d] + b_val[d] + b_rwse[d] + deg_emb[dg * DIM + d];
#pragma unroll
        for (int k = 0; k < RWSE_K; ++k) v += r[k] * w_rwse[k * DIM + d];
        h[i * DIM + d] = v;
        hb[i * DIM + d] = f2bf(v);
    } else if (b < 11250) {
        int e = (b - N_NODES) * 256 + tid;
        if (e < N_EDGES) atomicAdd(&cnt_arr[ei[N_EDGES + e]], 1);
    } else if (b < 11890) {
        int w_id = b - 11250;
        int l = w_id >> 7;
        int rem = w_id & 127;
        int mat = rem >> 6;
        int tile = rem & 63;
        const float* W  = (mat ? w2  : w1)  + (size_t)l * DIM * DIM;
        ushort*      Wt = (mat ? wt2 : wt1) + (size_t)l * DIM * DIM;
        int k0 = (tile >> 3) * 32, n0 = (tile & 7) * 32;
        int tx = tid & 31, ty = tid >> 5;
#pragma unroll
        for (int j = 0; j < 4; ++j)
            t[ty + j * 8][tx] = W[(k0 + ty + j * 8) * DIM + n0 + tx];
        __syncthreads();
#pragma unroll
        for (int j = 0; j < 4; ++j)
            Wt[(n0 + ty + j * 8) * DIM + k0 + tx] = f2bf(t[tx][ty + j * 8]);
    } else {
        int l = b - 11890;
        int idx = l * DIM + tid;
        float s = gamma[idx] * rsqrtf(var[idx] + 1e-5f);
        scale[idx] = s;
        shift[idx] = beta[idx] + (b2[idx] - mean[idx]) * s;
    }
}

// exclusive scan of cnt_arr into cur (single block, wave-shuffle based)
__global__ __launch_bounds__(1024)
void scan_kernel(const int* __restrict__ cnt_arr, int* __restrict__ cur, int n) {
    __shared__ int wsum[16];
    __shared__ int carry_sh;
    int tid = threadIdx.x, wave = tid >> 6, lane = tid & 63;
    if (tid == 0) carry_sh = 0;
    __syncthreads();
    for (int base = 0; base < n; base += 1024) {
        int idx = base + tid;
        int v = (idx < n) ? cnt_arr[idx] : 0;
        int s = v;
#pragma unroll
        for (int off = 1; off < 64; off <<= 1) {
            int t = __shfl_up(s, off, 64);
            if (lane >= off) s += t;
        }
        if (lane == 63) wsum[wave] = s;
        __syncthreads();
        if (wave == 0) {
            int ws = (lane < 16) ? wsum[lane] : 0;
#pragma unroll
            for (int off = 1; off < 16; off <<= 1) {
                int t = __shfl_up(ws, off, 64);
                if (lane >= off) ws += t;
            }
            if (lane < 16) wsum[lane] = ws;
        }
        __syncthreads();
        int excl = s - v + (wave ? wsum[wave - 1] : 0) + carry_sh;
        if (idx < n) cur[idx] = excl;
        __syncthreads();
        if (tid == 0) carry_sh += wsum[15];
        __syncthreads();
    }
}

__global__ __launch_bounds__(256)
void fill_kernel(const int* __restrict__ ei, int* __restrict__ cur,
                 int* __restrict__ cs) {
    int e = blockIdx.x * 256 + threadIdx.x;
    if (e < N_EDGES) {
        int d = ei[N_EDGES + e];
        int p = atomicAdd(&cur[d], 1);
        cs[p] = ei[e];
    }
}

// ---------------- aggregation ----------------
// one wave per node; edge indices via wave-uniform scalar loads;
// lanes 0-31 handle even neighbor, 32-63 odd; uint4 (16B) per lane.
#define ACCV(v)                                                        \
    acc[0] += bfbits2f((v).x << 16); acc[1] += bfbits2f((v).x & 0xffff0000u); \
    acc[2] += bfbits2f((v).y << 16); acc[3] += bfbits2f((v).y & 0xffff0000u); \
    acc[4] += bfbits2f((v).z << 16); acc[5] += bfbits2f((v).z & 0xffff0000u); \
    acc[6] += bfbits2f((v).w << 16); acc[7] += bfbits2f((v).w & 0xffff0000u);

__global__ __launch_bounds__(256)
void agg_kernel(const float* __restrict__ h, const ushort* __restrict__ hb,
                const int* __restrict__ cur, const int* __restrict__ cs,
                const float* __restrict__ eps_gin, int layer,
                ushort* __restrict__ y) {
    int wave = threadIdx.x >> 6;
    int lane = threadIdx.x & 63;
    int half = lane >> 5;
    int sl   = lane & 31;
    int i = blockIdx.x * 4 + wave;
    if (i >= N_NODES) return;
    const uint4* hb4 = (const uint4*)hb;   // row = 32 uint4
    float acc[8];
#pragma unroll
    for (int t = 0; t < 8; ++t) acc[t] = 0.f;

    int e0 = i ? cur[i - 1] : 0;
    int e1 = cur[i];
    e0 = __builtin_amdgcn_readfirstlane(e0);
    e1 = __builtin_amdgcn_readfirstlane(e1);

    int e = e0;
    for (; e + 8 <= e1; e += 8) {
        int n0 = cs[e + 0], n1 = cs[e + 1], n2 = cs[e + 2], n3 = cs[e + 3];
        int n4 = cs[e + 4], n5 = cs[e + 5], n6 = cs[e + 6], n7 = cs[e + 7];
        int s0 = half ? n1 : n0;
        int s1 = half ? n3 : n2;
        int s2 = half ? n5 : n4;
        int s3 = half ? n7 : n6;
        uint4 v0 = hb4[(size_t)s0 * 32 + sl];
        uint4 v1 = hb4[(size_t)s1 * 32 + sl];
        uint4 v2 = hb4[(size_t)s2 * 32 + sl];
        uint4 v3 = hb4[(size_t)s3 * 32 + sl];
        ACCV(v0); ACCV(v1); ACCV(v2); ACCV(v3);
    }
    for (; e + 2 <= e1; e += 2) {
        int n0 = cs[e], n1 = cs[e + 1];
        int s = half ? n1 : n0;
        uint4 v = hb4[(size_t)s * 32 + sl];
        ACCV(v);
    }
    if (e < e1) {
        int n0 = cs[e];
        if (!half) {
            uint4 v = hb4[(size_t)n0 * 32 + sl];
            ACCV(v);
        }
    }
    // combine halves
#pragma unroll
    for (int t = 0; t < 8; ++t) acc[t] += __shfl_xor(acc[t], 32, 64);
    if (half == 0) {
        float sc = 1.0f + eps_gin[layer];
        const float4* h4 = (const float4*)h;
        float4 a0 = h4[(size_t)i * 64 + sl * 2];
        float4 a1 = h4[(size_t)i * 64 + sl * 2 + 1];
        acc[0] += a0.x * sc; acc[1] += a0.y * sc;
        acc[2] += a0.z * sc; acc[3] += a0.w * sc;
        acc[4] += a1.x * sc; acc[5] += a1.y * sc;
        acc[6] += a1.z * sc; acc[7] += a1.w * sc;
        uint4 o;
        o.x = (uint)f2bf(acc[0]) | ((uint)f2bf(acc[1]) << 16);
        o.y = (uint)f2bf(acc[2]) | ((uint)f2bf(acc[3]) << 16);
        o.z = (uint)f2bf(acc[4]) | ((uint)f2bf(acc[5]) << 16);
        o.w = (uint)f2bf(acc[6]) | ((uint)f2bf(acc[7]) << 16);
        ((uint4*)y)[(size_t)i * 32 + sl] = o;
    }
}

// ---------------- per-wave fused MLP: H = ReLU(BN(ReLU(A@W1+b1)@W2)) --------
// One wave (64-thread block) per 32 rows. B streamed from L2 (W1/W2 are
// 128 KB each, L2-resident). t kept in wave-private LDS -> NO barriers at all.
#define MROWS 32
#define MTILES ((N_NODES + MROWS - 1) / MROWS)

__global__ __launch_bounds__(64)
void mlp_kernel(const ushort* __restrict__ A, const ushort* __restrict__ Wt1,
                const float* __restrict__ b1, const ushort* __restrict__ Wt2,
                const float* __restrict__ bnsc, const float* __restrict__ bnsh,
                float* __restrict__ H, ushort* __restrict__ Hb, int nrows) {
    __shared__ __align__(16) ushort t_lds[MROWS][DIM + 8];
    int lane = threadIdx.x;
    int quad = lane >> 4, l16 = lane & 15;
    int row0 = blockIdx.x * MROWS;
    int r0 = row0 + l16;          // m-group 0 A row
    int r1 = row0 + 16 + l16;     // m-group 1 A row

    f32x4 acc[2][16];
#pragma unroll
    for (int mg = 0; mg < 2; ++mg)
#pragma unroll
        for (int tj = 0; tj < 16; ++tj) acc[mg][tj] = (f32x4){0.f, 0.f, 0.f, 0.f};

    const bf16x8 zf = (bf16x8){0, 0, 0, 0, 0, 0, 0, 0};

    // ---- GEMM1: t = relu(A@W1 + b1) ----
    for (int k0 = 0; k0 < DIM; k0 += 32) {
        int ko = k0 + quad * 8;
        bf16x8 a0 = (r0 < nrows) ? *(const bf16x8*)&A[(size_t)r0 * DIM + ko] : zf;
        bf16x8 a1 = (r1 < nrows) ? *(const bf16x8*)&A[(size_t)r1 * DIM + ko] : zf;
#pragma unroll
        for (int tj = 0; tj < 16; ++tj) {
            bf16x8 bfr = *(const bf16x8*)&Wt1[(size_t)(tj * 16 + l16) * DIM + ko];
            acc[0][tj] = __builtin_amdgcn_mfma_f32_16x16x32_bf16(a0, bfr, acc[0][tj], 0, 0, 0);
            acc[1][tj] = __builtin_amdgcn_mfma_f32_16x16x32_bf16(a1, bfr, acc[1][tj], 0, 0, 0);
        }
    }
#pragma unroll
    for (int tj = 0; tj < 16; ++tj) {
        int col = tj * 16 + l16;
        float bias = b1[col];
#pragma unroll
        for (int mg = 0; mg < 2; ++mg)
#pragma unroll
            for (int r = 0; r < 4; ++r)
                t_lds[mg * 16 + quad * 4 + r][col] = f2bf(fmaxf(acc[mg][tj][r] + bias, 0.f));
    }

    // ---- GEMM2: h = relu(bn(t@W2)) ----
#pragma unroll
    for (int mg = 0; mg < 2; ++mg)
#pragma unroll
        for (int tj = 0; tj < 16; ++tj) acc[mg][tj] = (f32x4){0.f, 0.f, 0.f, 0.f};
    for (int k0 = 0; k0 < DIM; k0 += 32) {
        int ko = k0 + quad * 8;
        bf16x8 a0 = *(const bf16x8*)&t_lds[l16][ko];
        bf16x8 a1 = *(const bf16x8*)&t_lds[16 + l16][ko];
#pragma unroll
        for (int tj = 0; tj < 16; ++tj) {
            bf16x8 bfr = *(const bf16x8*)&Wt2[(size_t)(tj * 16 + l16) * DIM + ko];
            acc[0][tj] = __builtin_amdgcn_mfma_f32_16x16x32_bf16(a0, bfr, acc[0][tj], 0, 0, 0);
            acc[1][tj] = __builtin_amdgcn_mfma_f32_16x16x32_bf16(a1, bfr, acc[1][tj], 0, 0, 0);
        }
    }
#pragma unroll
    for (int tj = 0; tj < 16; ++tj) {
        int col = tj * 16 + l16;
        float s = bnsc[col], sh = bnsh[col];
#pragma unroll
        for (int mg = 0; mg < 2; ++mg)
#pragma unroll
            for (int r = 0; r < 4; ++r) {
                int row = row0 + mg * 16 + quad * 4 + r;
                if (row < nrows) {
                    float v = fmaxf(acc[mg][tj][r] * s + sh, 0.f);
                    H[(size_t)row * DIM + col] = v;
                    if (Hb) Hb[(size_t)row * DIM + col] = f2bf(v);
                }
            }
    }
}

// ---------------- pooling: batch sorted -> per-graph contiguous range -------
__global__ __launch_bounds__(256)
void pool_kernel(const float* __restrict__ hfin, const int* __restrict__ batch,
                 float* __restrict__ out) {
    int g = blockIdx.x;
    int d = threadIdx.x;
    int l = 0, r = N_NODES;
    while (l < r) { int m = (l + r) >> 1; if (batch[m] < g) l = m + 1; else r = m; }
    int lo = l;
    r = N_NODES;
    while (l < r) { int m = (l + r) >> 1; if (batch[m] < g + 1) l = m + 1; else r = m; }
    int hi = l;
    float a0 = 0.f, a1 = 0.f, a2 = 0.f, a3 = 0.f;
    int i = lo;
    for (; i + 4 <= hi; i += 4) {
        a0 += hfin[(size_t)i * DIM + d];
        a1 += hfin[(size_t)(i + 1) * DIM + d];
        a2 += hfin[(size_t)(i + 2) * DIM + d];
        a3 += hfin[(size_t)(i + 3) * DIM + d];
    }
    for (; i < hi; ++i) a0 += hfin[(size_t)i * DIM + d];
    float c = (float)(hi - lo);
    if (c < 1.f) c = 1.f;
    out[g * DIM + d] = ((a0 + a1) + (a2 + a3)) / c;
}

// ---------------- launch ----------------
extern "C" void kernel_launch(void* const* d_in, const int* in_sizes, int n_in,
                              void* d_out, int out_size, void* d_ws, size_t ws_size,
                              hipStream_t stream) {
    const int*   feat_id  = (const int*)d_in[0];
    const int*   ei       = (const int*)d_in[1];
    const int*   batch    = (const int*)d_in[2];
    const float* rwse     = (const float*)d_in[3];
    const int*   in_deg   = (const int*)d_in[4];
    const float* w_val    = (const float*)d_in[5];
    const float* b_val    = (const float*)d_in[6];
    const float* w_rwse   = (const float*)d_in[7];
    const float* b_rwse   = (const float*)d_in[8];
    const float* deg_emb  = (const float*)d_in[9];
    const float* mlp_w1   = (const float*)d_in[10];
    const float* mlp_b1   = (const float*)d_in[11];
    const float* mlp_w2   = (const float*)d_in[12];
    const float* mlp_b2   = (const float*)d_in[13];
    const float* bn_gamma = (const float*)d_in[14];
    const float* bn_beta  = (const float*)d_in[15];
    const float* bn_mean  = (const float*)d_in[16];
    const float* bn_var   = (const float*)d_in[17];
    const float* eps_gin  = (const float*)d_in[18];

    float* out = (float*)d_out;
    float* out_h = out + N_GRAPHS * DIM;   // final h written by last mlp

    char* w = (char*)d_ws;
    float*  h   = (float*)w;                              // N*D f32
    ushort* hb  = (ushort*)(h + (size_t)N_NODES * DIM);   // N*D bf16
    ushort* y   = hb + (size_t)N_NODES * DIM;             // N*D bf16
    ushort* wt1 = y + (size_t)N_NODES * DIM;              // L*D*D bf16
    ushort* wt2 = wt1 + (size_t)N_LAYERS * DIM * DIM;     // L*D*D bf16
    int* cnt_arr = (int*)(wt2 + (size_t)N_LAYERS * DIM * DIM); // N
    int* cur     = cnt_arr + N_NODES;                     // N
    int* cs      = cur + N_NODES;                         // E
    float* bnsc  = (float*)(cs + N_EDGES);                // L*D
    float* bnsh  = bnsc + N_LAYERS * DIM;                 // L*D

    hipMemsetAsync(cnt_arr, 0, N_NODES * sizeof(int), stream);

    setup_kernel<<<11895, 256, 0, stream>>>(
        feat_id, rwse, in_deg, w_val, b_val, w_rwse, b_rwse, deg_emb, h, hb,
        ei, cnt_arr, mlp_w1, mlp_w2, wt1, wt2,
        bn_gamma, bn_beta, bn_mean, bn_var, mlp_b2, bnsc, bnsh);
    scan_kernel<<<1, 1024, 0, stream>>>(cnt_arr, cur, N_NODES);
    fill_kernel<<<(N_EDGES + 255) / 256, 256, 0, stream>>>(ei, cur, cs);

    for (int l = 0; l < N_LAYERS; ++l) {
        agg_kernel<<<(N_NODES + 3) / 4, 256, 0, stream>>>(h, hb, cur, cs, eps_gin, l, y);
        float* Hdst = (l == N_LAYERS - 1) ? out_h : h;
        ushort* Hbdst = (l == N_LAYERS - 1) ? nullptr : hb;
        mlp_kernel<<<MTILES, 64, 0, stream>>>(y, wt1 + (size_t)l * DIM * DIM,
                                              mlp_b1 + l * DIM,
                                              wt2 + (size_t)l * DIM * DIM,
                                              bnsc + l * DIM, bnsh + l * DIM,
                                              Hdst, Hbdst, N_NODES);
    }

    pool_kernel<<<N_GRAPHS, 256, 0, stream>>>(out_h, batch, out);
}

// Round 7
// 507.147 us; speedup vs baseline: 1.2028x; 1.2028x over previous
//
#include <hip/hip_runtime.h>
#include <hip/hip_bf16.h>

#define N_NODES 10000
#define N_EDGES 320000
#define DIM     256
#define N_LAYERS 5
#define N_GRAPHS 128
#define RWSE_K  16

// W LDS layout: 256 rows (n) x (256+8) bf16 (pad 8 -> 2-way bank conflicts, free)
#define WSTRIDE (DIM + 8)
#define WLDS_BYTES (DIM * WSTRIDE * 2)
#define MCHUNK 32
#define NCHUNK ((N_NODES + MCHUNK - 1) / MCHUNK)

typedef __bf16 bf16_t;
typedef bf16_t bf16x8 __attribute__((ext_vector_type(8)));
typedef float  f32x4  __attribute__((ext_vector_type(4)));

__device__ inline ushort f2bf(float f) {
    union { float f; unsigned u; } v; v.f = f;
    unsigned r = v.u + 0x7fff + ((v.u >> 16) & 1);
    return (ushort)(r >> 16);
}
__device__ inline float bfbits2f(unsigned hi16) {
    union { unsigned u; float f; } v; v.u = hi16;
    return v.f;
}

// ---------------- fused setup: embed + edge-count + weight conv + BN fold ----
__global__ __launch_bounds__(256)
void setup_kernel(const int* __restrict__ feat_id,
                  const float* __restrict__ rwse,
                  const int* __restrict__ in_deg,
                  const float* __restrict__ w_val,
                  const float* __restrict__ b_val,
                  const float* __restrict__ w_rwse,
                  const float* __restrict__ b_rwse,
                  const float* __restrict__ deg_emb,
                  float* __restrict__ h, ushort* __restrict__ hb,
                  const int* __restrict__ ei, int* __restrict__ cnt_arr,
                  const float* __restrict__ w1, const float* __restrict__ w2,
                  ushort* __restrict__ wt1, ushort* __restrict__ wt2,
                  const float* __restrict__ gamma, const float* __restrict__ beta,
                  const float* __restrict__ mean, const float* __restrict__ var,
                  const float* __restrict__ b2, float* __restrict__ scale,
                  float* __restrict__ shift) {
    __shared__ float r[RWSE_K];
    __shared__ float t[32][33];
    int b = blockIdx.x;
    int tid = threadIdx.x;
    if (b < N_NODES) {
        int i = b, d = tid;
        if (d < RWSE_K) r[d] = rwse[i * RWSE_K + d];
        __syncthreads();
        int hid = feat_id[i] & (DIM - 1);
        int dg = in_deg[i];
        dg = dg < 0 ? 0 : (dg > 1000 ? 1000 : dg);
        float v = w_val[hid * DIM + d] + b_val[d] + b_rwse[d] + deg_emb[dg * DIM + d];
#pragma unroll
        for (int k = 0; k < RWSE_K; ++k) v += r[k] * w_rwse[k * DIM + d];
        h[i * DIM + d] = v;
        hb[i * DIM + d] = f2bf(v);
    } else if (b < 11250) {
        int e = (b - N_NODES) * 256 + tid;
        if (e < N_EDGES) atomicAdd(&cnt_arr[ei[N_EDGES + e]], 1);
    } else if (b < 11890) {
        int w_id = b - 11250;
        int l = w_id >> 7;
        int rem = w_id & 127;
        int mat = rem >> 6;
        int tile = rem & 63;
        const float* W  = (mat ? w2  : w1)  + (size_t)l * DIM * DIM;
        ushort*      Wt = (mat ? wt2 : wt1) + (size_t)l * DIM * DIM;
        int k0 = (tile >> 3) * 32, n0 = (tile & 7) * 32;
        int tx = tid & 31, ty = tid >> 5;
#pragma unroll
        for (int j = 0; j < 4; ++j)
            t[ty + j * 8][tx] = W[(k0 + ty + j * 8) * DIM + n0 + tx];
        __syncthreads();
#pragma unroll
        for (int j = 0; j < 4; ++j)
            Wt[(n0 + ty + j * 8) * DIM + k0 + tx] = f2bf(t[tx][ty + j * 8]);
    } else {
        int l = b - 11890;
        int idx = l * DIM + tid;
        float s = gamma[idx] * rsqrtf(var[idx] + 1e-5f);
        scale[idx] = s;
        shift[idx] = beta[idx] + (b2[idx] - mean[idx]) * s;
    }
}

// exclusive scan of cnt_arr into cur (single block, wave-shuffle based)
__global__ __launch_bounds__(1024)
void scan_kernel(const int* __restrict__ cnt_arr, int* __restrict__ cur, int n) {
    __shared__ int wsum[16];
    __shared__ int carry_sh;
    int tid = threadIdx.x, wave = tid >> 6, lane = tid & 63;
    if (tid == 0) carry_sh = 0;
    __syncthreads();
    for (int base = 0; base < n; base += 1024) {
        int idx = base + tid;
        int v = (idx < n) ? cnt_arr[idx] : 0;
        int s = v;
#pragma unroll
        for (int off = 1; off < 64; off <<= 1) {
            int t = __shfl_up(s, off, 64);
            if (lane >= off) s += t;
        }
        if (lane == 63) wsum[wave] = s;
        __syncthreads();
        if (wave == 0) {
            int ws = (lane < 16) ? wsum[lane] : 0;
#pragma unroll
            for (int off = 1; off < 16; off <<= 1) {
                int t = __shfl_up(ws, off, 64);
                if (lane >= off) ws += t;
            }
            if (lane < 16) wsum[lane] = ws;
        }
        __syncthreads();
        int excl = s - v + (wave ? wsum[wave - 1] : 0) + carry_sh;
        if (idx < n) cur[idx] = excl;
        __syncthreads();
        if (tid == 0) carry_sh += wsum[15];
        __syncthreads();
    }
}

__global__ __launch_bounds__(256)
void fill_kernel(const int* __restrict__ ei, int* __restrict__ cur,
                 int* __restrict__ cs) {
    int e = blockIdx.x * 256 + threadIdx.x;
    if (e < N_EDGES) {
        int d = ei[N_EDGES + e];
        int p = atomicAdd(&cur[d], 1);
        cs[p] = ei[e];
    }
}

// ---------------- aggregation (R5-proven shfl version) ----------------
#define ACCV(v)                                                        \
    acc[0] += bfbits2f((v).x << 16); acc[1] += bfbits2f((v).x & 0xffff0000u); \
    acc[2] += bfbits2f((v).y << 16); acc[3] += bfbits2f((v).y & 0xffff0000u); \
    acc[4] += bfbits2f((v).z << 16); acc[5] += bfbits2f((v).z & 0xffff0000u); \
    acc[6] += bfbits2f((v).w << 16); acc[7] += bfbits2f((v).w & 0xffff0000u);

__global__ __launch_bounds__(256)
void agg_kernel(const float* __restrict__ h, const ushort* __restrict__ hb,
                const int* __restrict__ cur, const int* __restrict__ cs,
                const float* __restrict__ eps_gin, int layer,
                ushort* __restrict__ y) {
    int wave = threadIdx.x >> 6;
    int lane = threadIdx.x & 63;
    int half = lane >> 5;
    int sl   = lane & 31;
    int i = blockIdx.x * 4 + wave;
    if (i >= N_NODES) return;
    const uint4* hb4 = (const uint4*)hb;   // row = 32 uint4
    float acc[8];
#pragma unroll
    for (int t = 0; t < 8; ++t) acc[t] = 0.f;

    int e0 = i ? cur[i - 1] : 0;
    int e1 = cur[i];
    for (int base = e0; base < e1; base += 64) {
        int rem = e1 - base;
        int cnt = rem < 64 ? rem : 64;
        int idx = (base + lane < e1) ? cs[base + lane] : 0;
        int j = 0;
        for (; j + 8 <= cnt; j += 8) {
            int s0 = __shfl(idx, j + half, 64);
            int s1 = __shfl(idx, j + 2 + half, 64);
            int s2 = __shfl(idx, j + 4 + half, 64);
            int s3 = __shfl(idx, j + 6 + half, 64);
            uint4 v0 = hb4[(size_t)s0 * 32 + sl];
            uint4 v1 = hb4[(size_t)s1 * 32 + sl];
            uint4 v2 = hb4[(size_t)s2 * 32 + sl];
            uint4 v3 = hb4[(size_t)s3 * 32 + sl];
            ACCV(v0); ACCV(v1); ACCV(v2); ACCV(v3);
        }
        for (; j + 2 <= cnt; j += 2) {
            int s = __shfl(idx, j + half, 64);
            uint4 v = hb4[(size_t)s * 32 + sl];
            ACCV(v);
        }
        if (j < cnt) {
            int s = __shfl(idx, j, 64);
            if (half == 0) {
                uint4 v = hb4[(size_t)s * 32 + sl];
                ACCV(v);
            }
        }
    }
#pragma unroll
    for (int t = 0; t < 8; ++t) acc[t] += __shfl_xor(acc[t], 32, 64);
    if (half == 0) {
        float sc = 1.0f + eps_gin[layer];
        const float4* h4 = (const float4*)h;
        float4 a0 = h4[(size_t)i * 64 + sl * 2];
        float4 a1 = h4[(size_t)i * 64 + sl * 2 + 1];
        acc[0] += a0.x * sc; acc[1] += a0.y * sc;
        acc[2] += a0.z * sc; acc[3] += a0.w * sc;
        acc[4] += a1.x * sc; acc[5] += a1.y * sc;
        acc[6] += a1.z * sc; acc[7] += a1.w * sc;
        uint4 o;
        o.x = (uint)f2bf(acc[0]) | ((uint)f2bf(acc[1]) << 16);
        o.y = (uint)f2bf(acc[2]) | ((uint)f2bf(acc[3]) << 16);
        o.z = (uint)f2bf(acc[4]) | ((uint)f2bf(acc[5]) << 16);
        o.w = (uint)f2bf(acc[6]) | ((uint)f2bf(acc[7]) << 16);
        ((uint4*)y)[(size_t)i * 32 + sl] = o;
    }
}

// ---------------- W-stationary GEMM: C = epilogue(A @ Wt^T) -----------------
// Whole Wt (256x256 bf16, [n][k]) loaded into LDS once (stride 264, 2-way
// conflicts only). 256 blocks = 1/CU (LDS-limited). Grid-stride over 32-row
// chunks; NO barriers in the chunk loop: A-fragments read straight from
// global (8 independent 16B loads, fully unrolled), B via ds_read_b128.
// Epilogue modes:
//   scale==null: relu(acc + shift[c])            -> outB (bf16)
//   scale!=null: relu(acc*scale[c] + shift[c])   -> outF (f32) and opt outB
__global__ __launch_bounds__(256)
void wgemm_kernel(const ushort* __restrict__ A, const ushort* __restrict__ Wt,
                  const float* __restrict__ scale, const float* __restrict__ shift,
                  float* __restrict__ outF, ushort* __restrict__ outB, int nrows) {
    extern __shared__ ushort wlds[];   // [DIM][WSTRIDE]
    int tid = threadIdx.x;
    int wave = tid >> 6, lane = tid & 63, quad = lane >> 4, l16 = lane & 15;
    int wr = (wave & 1) * 16;      // row strip within chunk
    int wc = (wave >> 1) * 128;    // col half

    // ---- load W into LDS (once) ----
    {
        int cchunk = tid & 31;         // which uint4 of the row
        int rbase  = tid >> 5;         // 0..7
        for (int r = rbase; r < DIM; r += 8) {
            uint4 v = *(const uint4*)&Wt[(size_t)r * DIM + cchunk * 8];
            *(uint4*)&wlds[r * WSTRIDE + cchunk * 8] = v;
        }
    }
    __syncthreads();

    const bf16x8 zf = (bf16x8){0, 0, 0, 0, 0, 0, 0, 0};

    for (int c = blockIdx.x; c < NCHUNK; c += gridDim.x) {
        int row0 = c * MCHUNK;
        int arow = row0 + wr + l16;
        // A-fragments: 8 independent 16B loads, all addresses known up front
        bf16x8 af[8];
#pragma unroll
        for (int s = 0; s < 8; ++s)
            af[s] = (arow < nrows)
                ? *(const bf16x8*)&A[(size_t)arow * DIM + s * 32 + quad * 8]
                : zf;
        f32x4 acc[8];
#pragma unroll
        for (int tj = 0; tj < 8; ++tj) acc[tj] = (f32x4){0.f, 0.f, 0.f, 0.f};
#pragma unroll
        for (int s = 0; s < 8; ++s) {
#pragma unroll
            for (int tj = 0; tj < 8; ++tj) {
                bf16x8 bfr = *(const bf16x8*)&wlds[(wc + tj * 16 + l16) * WSTRIDE + s * 32 + quad * 8];
                acc[tj] = __builtin_amdgcn_mfma_f32_16x16x32_bf16(af[s], bfr, acc[tj], 0, 0, 0);
            }
        }
        // epilogue
#pragma unroll
        for (int tj = 0; tj < 8; ++tj) {
            int col = wc + tj * 16 + l16;
            float sc = scale ? scale[col] : 1.f;
            float sh = shift[col];
#pragma unroll
            for (int r = 0; r < 4; ++r) {
                int row = row0 + wr + quad * 4 + r;
                if (row < nrows) {
                    float v = acc[tj][r];
                    v = scale ? v * sc + sh : v + sh;
                    v = fmaxf(v, 0.f);
                    if (outF) outF[(size_t)row * DIM + col] = v;
                    if (outB) outB[(size_t)row * DIM + col] = f2bf(v);
                }
            }
        }
    }
}

// ---------------- pooling: batch sorted -> per-graph contiguous range -------
__global__ __launch_bounds__(256)
void pool_kernel(const float* __restrict__ hfin, const int* __restrict__ batch,
                 float* __restrict__ out) {
    int g = blockIdx.x;
    int d = threadIdx.x;
    int l = 0, r = N_NODES;
    while (l < r) { int m = (l + r) >> 1; if (batch[m] < g) l = m + 1; else r = m; }
    int lo = l;
    r = N_NODES;
    while (l < r) { int m = (l + r) >> 1; if (batch[m] < g + 1) l = m + 1; else r = m; }
    int hi = l;
    float a0 = 0.f, a1 = 0.f, a2 = 0.f, a3 = 0.f;
    int i = lo;
    for (; i + 4 <= hi; i += 4) {
        a0 += hfin[(size_t)i * DIM + d];
        a1 += hfin[(size_t)(i + 1) * DIM + d];
        a2 += hfin[(size_t)(i + 2) * DIM + d];
        a3 += hfin[(size_t)(i + 3) * DIM + d];
    }
    for (; i < hi; ++i) a0 += hfin[(size_t)i * DIM + d];
    float c = (float)(hi - lo);
    if (c < 1.f) c = 1.f;
    out[g * DIM + d] = ((a0 + a1) + (a2 + a3)) / c;
}

// ---------------- launch ----------------
extern "C" void kernel_launch(void* const* d_in, const int* in_sizes, int n_in,
                              void* d_out, int out_size, void* d_ws, size_t ws_size,
                              hipStream_t stream) {
    const int*   feat_id  = (const int*)d_in[0];
    const int*   ei       = (const int*)d_in[1];
    const int*   batch    = (const int*)d_in[2];
    const float* rwse     = (const float*)d_in[3];
    const int*   in_deg   = (const int*)d_in[4];
    const float* w_val    = (const float*)d_in[5];
    const float* b_val    = (const float*)d_in[6];
    const float* w_rwse   = (const float*)d_in[7];
    const float* b_rwse   = (const float*)d_in[8];
    const float* deg_emb  = (const float*)d_in[9];
    const float* mlp_w1   = (const float*)d_in[10];
    const float* mlp_b1   = (const float*)d_in[11];
    const float* mlp_w2   = (const float*)d_in[12];
    const float* mlp_b2   = (const float*)d_in[13];
    const float* bn_gamma = (const float*)d_in[14];
    const float* bn_beta  = (const float*)d_in[15];
    const float* bn_mean  = (const float*)d_in[16];
    const float* bn_var   = (const float*)d_in[17];
    const float* eps_gin  = (const float*)d_in[18];

    float* out = (float*)d_out;
    float* out_h = out + N_GRAPHS * DIM;   // final h written by last wgemm

    char* w = (char*)d_ws;
    float*  h   = (float*)w;                              // N*D f32
    ushort* hb  = (ushort*)(h + (size_t)N_NODES * DIM);   // N*D bf16
    ushort* y   = hb + (size_t)N_NODES * DIM;             // N*D bf16
    ushort* t   = y + (size_t)N_NODES * DIM;              // N*D bf16
    ushort* wt1 = t + (size_t)N_NODES * DIM;              // L*D*D bf16
    ushort* wt2 = wt1 + (size_t)N_LAYERS * DIM * DIM;     // L*D*D bf16
    int* cnt_arr = (int*)(wt2 + (size_t)N_LAYERS * DIM * DIM); // N
    int* cur     = cnt_arr + N_NODES;                     // N
    int* cs      = cur + N_NODES;                         // E
    float* bnsc  = (float*)(cs + N_EDGES);                // L*D
    float* bnsh  = bnsc + N_LAYERS * DIM;                 // L*D

    // allow >64KB dynamic LDS for the W-stationary GEMM (host-side, capture-safe)
    hipFuncSetAttribute((const void*)wgemm_kernel,
                        hipFuncAttributeMaxDynamicSharedMemorySize, WLDS_BYTES);

    hipMemsetAsync(cnt_arr, 0, N_NODES * sizeof(int), stream);

    setup_kernel<<<11895, 256, 0, stream>>>(
        feat_id, rwse, in_deg, w_val, b_val, w_rwse, b_rwse, deg_emb, h, hb,
        ei, cnt_arr, mlp_w1, mlp_w2, wt1, wt2,
        bn_gamma, bn_beta, bn_mean, bn_var, mlp_b2, bnsc, bnsh);
    scan_kernel<<<1, 1024, 0, stream>>>(cnt_arr, cur, N_NODES);
    fill_kernel<<<(N_EDGES + 255) / 256, 256, 0, stream>>>(ei, cur, cs);

    for (int l = 0; l < N_LAYERS; ++l) {
        agg_kernel<<<(N_NODES + 3) / 4, 256, 0, stream>>>(h, hb, cur, cs, eps_gin, l, y);
        // GEMM1: t = relu(y@W1 + b1)   (bf16 out only)
        wgemm_kernel<<<256, 256, WLDS_BYTES, stream>>>(
            y, wt1 + (size_t)l * DIM * DIM,
            nullptr, mlp_b1 + l * DIM,
            nullptr, t, N_NODES);
        // GEMM2: h = relu(bn(t@W2))    (f32 + bf16 mirror; last layer -> out)
        float* Hdst = (l == N_LAYERS - 1) ? out_h : h;
        ushort* Hbdst = (l == N_LAYERS - 1) ? nullptr : hb;
        wgemm_kernel<<<256, 256, WLDS_BYTES, stream>>>(
            t, wt2 + (size_t)l * DIM * DIM,
            bnsc + l * DIM, bnsh + l * DIM,
            Hdst, Hbdst, N_NODES);
    }

    pool_kernel<<<N_GRAPHS, 256, 0, stream>>>(out_h, batch, out);
}

// Round 8
// 382.104 us; speedup vs baseline: 1.5964x; 1.3272x over previous
//
#include <hip/hip_runtime.h>
#include <hip/hip_bf16.h>

#define N_NODES 10000
#define N_EDGES 320000
#define DIM     256
#define HDIM    128
#define N_LAYERS 5
#define N_GRAPHS 128
#define RWSE_K  16

typedef __bf16 bf16_t;
typedef bf16_t bf16x8 __attribute__((ext_vector_type(8)));
typedef float  f32x4  __attribute__((ext_vector_type(4)));

__device__ inline ushort f2bf(float f) {
    union { float f; unsigned u; } v; v.f = f;
    unsigned r = v.u + 0x7fff + ((v.u >> 16) & 1);
    return (ushort)(r >> 16);
}
__device__ inline float bfbits2f(unsigned hi16) {
    union { unsigned u; float f; } v; v.u = hi16;
    return v.f;
}

// ---------------- fused setup: embed + edge-count + weight conv + BN fold ----
__global__ __launch_bounds__(256)
void setup_kernel(const int* __restrict__ feat_id,
                  const float* __restrict__ rwse,
                  const int* __restrict__ in_deg,
                  const float* __restrict__ w_val,
                  const float* __restrict__ b_val,
                  const float* __restrict__ w_rwse,
                  const float* __restrict__ b_rwse,
                  const float* __restrict__ deg_emb,
                  ushort* __restrict__ hb_lo, ushort* __restrict__ hb_hi,
                  const int* __restrict__ ei, int* __restrict__ cnt_arr,
                  const float* __restrict__ w1, const float* __restrict__ w2,
                  ushort* __restrict__ wt1, ushort* __restrict__ wt2,
                  const float* __restrict__ gamma, const float* __restrict__ beta,
                  const float* __restrict__ mean, const float* __restrict__ var,
                  const float* __restrict__ b2, float* __restrict__ scale,
                  float* __restrict__ shift) {
    __shared__ float r[RWSE_K];
    __shared__ float t[32][33];
    int b = blockIdx.x;
    int tid = threadIdx.x;
    if (b < N_NODES) {
        int i = b, d = tid;
        if (d < RWSE_K) r[d] = rwse[i * RWSE_K + d];
        __syncthreads();
        int hid = feat_id[i] & (DIM - 1);
        int dg = in_deg[i];
        dg = dg < 0 ? 0 : (dg > 1000 ? 1000 : dg);
        float v = w_val[hid * DIM + d] + b_val[d] + b_rwse[d] + deg_emb[dg * DIM + d];
#pragma unroll
        for (int k = 0; k < RWSE_K; ++k) v += r[k] * w_rwse[k * DIM + d];
        int hh = d >> 7, dl = d & (HDIM - 1);
        (hh ? hb_hi : hb_lo)[i * HDIM + dl] = f2bf(v);
    } else if (b < 11250) {
        int e = (b - N_NODES) * 256 + tid;
        if (e < N_EDGES) atomicAdd(&cnt_arr[ei[N_EDGES + e]], 1);
    } else if (b < 11890) {
        int w_id = b - 11250;
        int l = w_id >> 7;
        int rem = w_id & 127;
        int mat = rem >> 6;
        int tile = rem & 63;
        const float* W  = (mat ? w2  : w1)  + (size_t)l * DIM * DIM;
        ushort*      Wt = (mat ? wt2 : wt1) + (size_t)l * DIM * DIM;
        int k0 = (tile >> 3) * 32, n0 = (tile & 7) * 32;
        int tx = tid & 31, ty = tid >> 5;
#pragma unroll
        for (int j = 0; j < 4; ++j)
            t[ty + j * 8][tx] = W[(k0 + ty + j * 8) * DIM + n0 + tx];
        __syncthreads();
#pragma unroll
        for (int j = 0; j < 4; ++j)
            Wt[(n0 + ty + j * 8) * DIM + k0 + tx] = f2bf(t[tx][ty + j * 8]);
    } else {
        int l = b - 11890;
        int idx = l * DIM + tid;
        float s = gamma[idx] * rsqrtf(var[idx] + 1e-5f);
        scale[idx] = s;
        shift[idx] = beta[idx] + (b2[idx] - mean[idx]) * s;
    }
}

// exclusive scan of cnt_arr into cur (single block, wave-shuffle based)
__global__ __launch_bounds__(1024)
void scan_kernel(const int* __restrict__ cnt_arr, int* __restrict__ cur, int n) {
    __shared__ int wsum[16];
    __shared__ int carry_sh;
    int tid = threadIdx.x, wave = tid >> 6, lane = tid & 63;
    if (tid == 0) carry_sh = 0;
    __syncthreads();
    for (int base = 0; base < n; base += 1024) {
        int idx = base + tid;
        int v = (idx < n) ? cnt_arr[idx] : 0;
        int s = v;
#pragma unroll
        for (int off = 1; off < 64; off <<= 1) {
            int t = __shfl_up(s, off, 64);
            if (lane >= off) s += t;
        }
        if (lane == 63) wsum[wave] = s;
        __syncthreads();
        if (wave == 0) {
            int ws = (lane < 16) ? wsum[lane] : 0;
#pragma unroll
            for (int off = 1; off < 16; off <<= 1) {
                int t = __shfl_up(ws, off, 64);
                if (lane >= off) ws += t;
            }
            if (lane < 16) wsum[lane] = ws;
        }
        __syncthreads();
        int excl = s - v + (wave ? wsum[wave - 1] : 0) + carry_sh;
        if (idx < n) cur[idx] = excl;
        __syncthreads();
        if (tid == 0) carry_sh += wsum[15];
        __syncthreads();
    }
}

__global__ __launch_bounds__(256)
void fill_kernel(const int* __restrict__ ei, int* __restrict__ cur,
                 int* __restrict__ cs) {
    int e = blockIdx.x * 256 + threadIdx.x;
    if (e < N_EDGES) {
        int d = ei[N_EDGES + e];
        int p = atomicAdd(&cur[d], 1);
        cs[p] = ei[e];
    }
}

// ---------------- aggregation over ONE channel half (L2-resident) ----------
// One wave per node. Half-row = 128 ch = 16 uint4; quarter q (lane>>4)
// handles neighbor j+q -> 4 neighbors per instruction, x2 unrolled.
#define ACCV(v)                                                        \
    acc[0] += bfbits2f((v).x << 16); acc[1] += bfbits2f((v).x & 0xffff0000u); \
    acc[2] += bfbits2f((v).y << 16); acc[3] += bfbits2f((v).y & 0xffff0000u); \
    acc[4] += bfbits2f((v).z << 16); acc[5] += bfbits2f((v).z & 0xffff0000u); \
    acc[6] += bfbits2f((v).w << 16); acc[7] += bfbits2f((v).w & 0xffff0000u);

__global__ __launch_bounds__(256)
void agg_kernel(const ushort* __restrict__ hbH,   // [N][128] bf16 half
                const int* __restrict__ cur, const int* __restrict__ cs,
                const float* __restrict__ eps_gin, int layer, int hh,
                ushort* __restrict__ y) {          // [N][256] bf16, cols hh*128..
    int wave = threadIdx.x >> 6;
    int lane = threadIdx.x & 63;
    int quarter = lane >> 4;
    int sl = lane & 15;
    int i = blockIdx.x * 4 + wave;
    if (i >= N_NODES) return;
    const uint4* hb4 = (const uint4*)hbH;   // row = 16 uint4
    float acc[8];
#pragma unroll
    for (int t = 0; t < 8; ++t) acc[t] = 0.f;

    int e0 = i ? cur[i - 1] : 0;
    int e1 = cur[i];
    for (int base = e0; base < e1; base += 64) {
        int rem = e1 - base;
        int cnt = rem < 64 ? rem : 64;
        int idx = (base + lane < e1) ? cs[base + lane] : 0;
        int j = 0;
        for (; j + 8 <= cnt; j += 8) {
            int s0 = __shfl(idx, j + quarter, 64);
            int s1 = __shfl(idx, j + 4 + quarter, 64);
            uint4 v0 = hb4[(size_t)s0 * 16 + sl];
            uint4 v1 = hb4[(size_t)s1 * 16 + sl];
            ACCV(v0); ACCV(v1);
        }
        for (; j + 4 <= cnt; j += 4) {
            int s = __shfl(idx, j + quarter, 64);
            uint4 v = hb4[(size_t)s * 16 + sl];
            ACCV(v);
        }
        for (; j < cnt; ++j) {
            int s = __shfl(idx, j, 64);
            if (quarter == 0) {
                uint4 v = hb4[(size_t)s * 16 + sl];
                ACCV(v);
            }
        }
    }
    // reduce quarters
#pragma unroll
    for (int t = 0; t < 8; ++t) acc[t] += __shfl_xor(acc[t], 16, 64);
#pragma unroll
    for (int t = 0; t < 8; ++t) acc[t] += __shfl_xor(acc[t], 32, 64);
    if (quarter == 0) {
        float sc = 1.0f + eps_gin[layer];
        uint4 sv = hb4[(size_t)i * 16 + sl];     // self term (bf16)
        acc[0] += bfbits2f(sv.x << 16) * sc; acc[1] += bfbits2f(sv.x & 0xffff0000u) * sc;
        acc[2] += bfbits2f(sv.y << 16) * sc; acc[3] += bfbits2f(sv.y & 0xffff0000u) * sc;
        acc[4] += bfbits2f(sv.z << 16) * sc; acc[5] += bfbits2f(sv.z & 0xffff0000u) * sc;
        acc[6] += bfbits2f(sv.w << 16) * sc; acc[7] += bfbits2f(sv.w & 0xffff0000u) * sc;
        uint4 o;
        o.x = (uint)f2bf(acc[0]) | ((uint)f2bf(acc[1]) << 16);
        o.y = (uint)f2bf(acc[2]) | ((uint)f2bf(acc[3]) << 16);
        o.z = (uint)f2bf(acc[4]) | ((uint)f2bf(acc[5]) << 16);
        o.w = (uint)f2bf(acc[6]) | ((uint)f2bf(acc[7]) << 16);
        ((uint4*)y)[(size_t)i * 32 + hh * 16 + sl] = o;
    }
}

// ---------------- fused MLP: out = ReLU(BN(ReLU(A@W1+b1)@W2)) ---------------
// R5-proven structure: 32 rows x 256 cols, 4 waves, t in LDS.
// Epilogue: layers 0..3 -> bf16 halves only; last layer -> f32 out_h only.
#define GBM 32

__global__ __launch_bounds__(256)
void gemm12_kernel(const ushort* __restrict__ A, const ushort* __restrict__ Wt1,
                   const float* __restrict__ b1, const ushort* __restrict__ Wt2,
                   const float* __restrict__ bnsc, const float* __restrict__ bnsh,
                   float* __restrict__ outF, ushort* __restrict__ hbl,
                   ushort* __restrict__ hbh, int nrows) {
    __shared__ __align__(16) ushort As[GBM][40];
    __shared__ __align__(16) ushort Bs[DIM][40];
    __shared__ __align__(16) ushort Ts[GBM][DIM + 8];
    int tx = threadIdx.x;
    int row0 = blockIdx.x * GBM;
    int wave = tx >> 6, lane = tx & 63, quad = lane >> 4, l16 = lane & 15;
    int wr = (wave >> 1) * 16;
    int wc = (wave & 1) * 128;
    int srow = tx >> 2;
    int skol = (tx & 3) * 8;

    f32x4 acc[8];
#pragma unroll
    for (int t = 0; t < 8; ++t) acc[t] = (f32x4){0.f, 0.f, 0.f, 0.f};

    for (int k0 = 0; k0 < DIM; k0 += 32) {
        if (tx < 128) {
            int arow = row0 + srow;
            uint4 av = make_uint4(0u, 0u, 0u, 0u);
            if (arow < nrows) av = *(const uint4*)&A[(size_t)arow * DIM + k0 + skol];
            *(uint4*)&As[srow][skol] = av;
        }
#pragma unroll
        for (int j = 0; j < 4; ++j) {
            int r = srow + 64 * j;
            *(uint4*)&Bs[r][skol] = *(const uint4*)&Wt1[(size_t)r * DIM + k0 + skol];
        }
        __syncthreads();
        bf16x8 af = *(const bf16x8*)&As[wr + l16][quad * 8];
#pragma unroll
        for (int tj = 0; tj < 8; ++tj) {
            bf16x8 bf = *(const bf16x8*)&Bs[wc + tj * 16 + l16][quad * 8];
            acc[tj] = __builtin_amdgcn_mfma_f32_16x16x32_bf16(af, bf, acc[tj], 0, 0, 0);
        }
        __syncthreads();
    }
#pragma unroll
    for (int tj = 0; tj < 8; ++tj) {
        int col = wc + tj * 16 + l16;
        float bias = b1[col];
#pragma unroll
        for (int r = 0; r < 4; ++r) {
            int rl = wr + quad * 4 + r;
            Ts[rl][col] = f2bf(fmaxf(acc[tj][r] + bias, 0.f));
        }
    }
    __syncthreads();

#pragma unroll
    for (int t = 0; t < 8; ++t) acc[t] = (f32x4){0.f, 0.f, 0.f, 0.f};
    for (int k0 = 0; k0 < DIM; k0 += 32) {
#pragma unroll
        for (int j = 0; j < 4; ++j) {
            int r = srow + 64 * j;
            *(uint4*)&Bs[r][skol] = *(const uint4*)&Wt2[(size_t)r * DIM + k0 + skol];
        }
        __syncthreads();
        bf16x8 af = *(const bf16x8*)&Ts[wr + l16][k0 + quad * 8];
#pragma unroll
        for (int tj = 0; tj < 8; ++tj) {
            bf16x8 bf = *(const bf16x8*)&Bs[wc + tj * 16 + l16][quad * 8];
            acc[tj] = __builtin_amdgcn_mfma_f32_16x16x32_bf16(af, bf, acc[tj], 0, 0, 0);
        }
        __syncthreads();
    }
#pragma unroll
    for (int tj = 0; tj < 8; ++tj) {
        int col = wc + tj * 16 + l16;
        float s = bnsc[col], sh = bnsh[col];
#pragma unroll
        for (int r = 0; r < 4; ++r) {
            int row = row0 + wr + quad * 4 + r;
            if (row < nrows) {
                float v = fmaxf(acc[tj][r] * s + sh, 0.f);
                if (outF) outF[(size_t)row * DIM + col] = v;
                if (hbl) {
                    if (col < HDIM) hbl[(size_t)row * HDIM + col] = f2bf(v);
                    else            hbh[(size_t)row * HDIM + col - HDIM] = f2bf(v);
                }
            }
        }
    }
}

// ---------------- pooling: batch sorted -> per-graph contiguous range -------
__global__ __launch_bounds__(256)
void pool_kernel(const float* __restrict__ hfin, const int* __restrict__ batch,
                 float* __restrict__ out) {
    int g = blockIdx.x;
    int d = threadIdx.x;
    int l = 0, r = N_NODES;
    while (l < r) { int m = (l + r) >> 1; if (batch[m] < g) l = m + 1; else r = m; }
    int lo = l;
    r = N_NODES;
    while (l < r) { int m = (l + r) >> 1; if (batch[m] < g + 1) l = m + 1; else r = m; }
    int hi = l;
    float a0 = 0.f, a1 = 0.f, a2 = 0.f, a3 = 0.f;
    int i = lo;
    for (; i + 4 <= hi; i += 4) {
        a0 += hfin[(size_t)i * DIM + d];
        a1 += hfin[(size_t)(i + 1) * DIM + d];
        a2 += hfin[(size_t)(i + 2) * DIM + d];
        a3 += hfin[(size_t)(i + 3) * DIM + d];
    }
    for (; i < hi; ++i) a0 += hfin[(size_t)i * DIM + d];
    float c = (float)(hi - lo);
    if (c < 1.f) c = 1.f;
    out[g * DIM + d] = ((a0 + a1) + (a2 + a3)) / c;
}

// ---------------- launch ----------------
extern "C" void kernel_launch(void* const* d_in, const int* in_sizes, int n_in,
                              void* d_out, int out_size, void* d_ws, size_t ws_size,
                              hipStream_t stream) {
    const int*   feat_id  = (const int*)d_in[0];
    const int*   ei       = (const int*)d_in[1];
    const int*   batch    = (const int*)d_in[2];
    const float* rwse     = (const float*)d_in[3];
    const int*   in_deg   = (const int*)d_in[4];
    const float* w_val    = (const float*)d_in[5];
    const float* b_val    = (const float*)d_in[6];
    const float* w_rwse   = (const float*)d_in[7];
    const float* b_rwse   = (const float*)d_in[8];
    const float* deg_emb  = (const float*)d_in[9];
    const float* mlp_w1   = (const float*)d_in[10];
    const float* mlp_b1   = (const float*)d_in[11];
    const float* mlp_w2   = (const float*)d_in[12];
    const float* mlp_b2   = (const float*)d_in[13];
    const float* bn_gamma = (const float*)d_in[14];
    const float* bn_beta  = (const float*)d_in[15];
    const float* bn_mean  = (const float*)d_in[16];
    const float* bn_var   = (const float*)d_in[17];
    const float* eps_gin  = (const float*)d_in[18];

    float* out = (float*)d_out;
    float* out_h = out + N_GRAPHS * DIM;   // final h (f32) written by last gemm12

    char* w = (char*)d_ws;
    ushort* hb_lo = (ushort*)w;                               // N*128 bf16
    ushort* hb_hi = hb_lo + (size_t)N_NODES * HDIM;           // N*128 bf16
    ushort* y     = hb_hi + (size_t)N_NODES * HDIM;           // N*256 bf16
    ushort* wt1   = y + (size_t)N_NODES * DIM;                // L*D*D bf16
    ushort* wt2   = wt1 + (size_t)N_LAYERS * DIM * DIM;       // L*D*D bf16
    int* cnt_arr  = (int*)(wt2 + (size_t)N_LAYERS * DIM * DIM); // N
    int* cur      = cnt_arr + N_NODES;                        // N
    int* cs       = cur + N_NODES;                            // E
    float* bnsc   = (float*)(cs + N_EDGES);                   // L*D
    float* bnsh   = bnsc + N_LAYERS * DIM;                    // L*D

    hipMemsetAsync(cnt_arr, 0, N_NODES * sizeof(int), stream);

    setup_kernel<<<11895, 256, 0, stream>>>(
        feat_id, rwse, in_deg, w_val, b_val, w_rwse, b_rwse, deg_emb,
        hb_lo, hb_hi, ei, cnt_arr, mlp_w1, mlp_w2, wt1, wt2,
        bn_gamma, bn_beta, bn_mean, bn_var, mlp_b2, bnsc, bnsh);
    scan_kernel<<<1, 1024, 0, stream>>>(cnt_arr, cur, N_NODES);
    fill_kernel<<<(N_EDGES + 255) / 256, 256, 0, stream>>>(ei, cur, cs);

    int agrid = (N_NODES + 3) / 4;
    int ggrid = (N_NODES + GBM - 1) / GBM;
    for (int l = 0; l < N_LAYERS; ++l) {
        agg_kernel<<<agrid, 256, 0, stream>>>(hb_lo, cur, cs, eps_gin, l, 0, y);
        agg_kernel<<<agrid, 256, 0, stream>>>(hb_hi, cur, cs, eps_gin, l, 1, y);
        bool last = (l == N_LAYERS - 1);
        gemm12_kernel<<<ggrid, 256, 0, stream>>>(
            y, wt1 + (size_t)l * DIM * DIM, mlp_b1 + l * DIM,
            wt2 + (size_t)l * DIM * DIM, bnsc + l * DIM, bnsh + l * DIM,
            last ? out_h : nullptr,
            last ? nullptr : hb_lo, last ? nullptr : hb_hi, N_NODES);
    }

    pool_kernel<<<N_GRAPHS, 256, 0, stream>>>(out_h, batch, out);
}